// Round 1
// baseline (140.647 us; speedup 1.0000x reference)
//
#include <hip/hip_runtime.h>
#include <math.h>

// Problem constants (from reference setup_inputs)
#define BATCH   2
#define NBOX    512
#define KTOT    (BATCH * NBOX)   // 1024 ROIs
#define CCH     256
#define OUTHW   7
#define PIX     (OUTHW * OUTHW)  // 49
// per-(k,c) pixels * channels = 49*256 = 12544 = 196 waves exactly -> wave-uniform k

__global__ __launch_bounds__(256) void msroi_kernel(
    const float* __restrict__ f0,   // [2,256,200,200]
    const float* __restrict__ f1,   // [2,256,100,100]
    const float* __restrict__ f2,   // [2,256, 50, 50]
    const float* __restrict__ f3,   // [2,256, 25, 25]
    const float* __restrict__ boxes, // [K,4] xyxy image coords
    float* __restrict__ out)         // [K,256,7,7]
{
    const int t = blockIdx.x * blockDim.x + threadIdx.x;
    const int total = KTOT * CCH * PIX;
    if (t >= total) return;

    const int p  = t % PIX;
    const int c  = (t / PIX) % CCH;
    const int k  = t / (PIX * CCH);
    const int ph = p / OUTHW;
    const int pw = p % OUTHW;

    // --- box + level select (wave-uniform: whole wave shares k) ---
    const float bx1 = boxes[k * 4 + 0];
    const float by1 = boxes[k * 4 + 1];
    const float bx2 = boxes[k * 4 + 2];
    const float by2 = boxes[k * 4 + 3];

    const float area = fmaxf((bx2 - bx1) * (by2 - by1), 0.0f);
    const float s    = sqrtf(area);
    float lvlf = floorf(4.0f + log2f(s / 224.0f) + 1e-6f);
    lvlf = fminf(fmaxf(lvlf, 2.0f), 5.0f);   // clip BEFORE int cast (handles -inf)
    const int lvl = (int)lvlf - 2;           // 0..3

    const float* feat;
    int H, W;
    float scale;
    switch (lvl) {
        case 0:  feat = f0; H = 200; W = 200; scale = 0.25f;    break;
        case 1:  feat = f1; H = 100; W = 100; scale = 0.125f;   break;
        case 2:  feat = f2; H =  50; W =  50; scale = 0.0625f;  break;
        default: feat = f3; H =  25; W =  25; scale = 0.03125f; break;
    }

    const int b = k / NBOX;
    const float* __restrict__ fc = feat + ((size_t)(b * CCH + c)) * (size_t)(H * W);

    // --- roi geometry in feature coords ---
    const float rx1 = bx1 * scale;
    const float ry1 = by1 * scale;
    const float rx2 = bx2 * scale;
    const float ry2 = by2 * scale;
    const float roi_w = fmaxf(rx2 - rx1, 1.0f);
    const float roi_h = fmaxf(ry2 - ry1, 1.0f);
    const float bin_w = roi_w / (float)OUTHW;
    const float bin_h = roi_h / (float)OUTHW;

    const float Hf = (float)H, Wf = (float)W;

    float acc = 0.0f;
    #pragma unroll
    for (int sy = 0; sy < 2; ++sy) {
        // y = y1 + ph*bin_h + (sy+0.5)*bin_h/2   (match reference op order)
        const float y  = ry1 + (float)ph * bin_h + ((float)sy + 0.5f) * bin_h / 2.0f;
        const bool  vy = (y >= -1.0f) && (y <= Hf);
        const float yc = fminf(fmaxf(y, 0.0f), Hf - 1.0f);
        int yl = (int)floorf(yc);
        yl = min(max(yl, 0), H - 2);
        const float ly = yc - (float)yl;

        #pragma unroll
        for (int sx = 0; sx < 2; ++sx) {
            const float x  = rx1 + (float)pw * bin_w + ((float)sx + 0.5f) * bin_w / 2.0f;
            const bool  vx = (x >= -1.0f) && (x <= Wf);
            const float xc = fminf(fmaxf(x, 0.0f), Wf - 1.0f);
            int xl = (int)floorf(xc);
            xl = min(max(xl, 0), W - 2);
            const float lx = xc - (float)xl;

            if (vy && vx) {
                const float* p00 = fc + (size_t)yl * W + xl;
                const float v00 = p00[0];
                const float v01 = p00[1];
                const float v10 = p00[W];
                const float v11 = p00[W + 1];
                const float v =
                    (1.0f - ly) * (1.0f - lx) * v00 +
                    (1.0f - ly) * lx          * v01 +
                    ly          * (1.0f - lx) * v10 +
                    ly          * lx          * v11;
                acc += v;
            }
        }
    }

    out[t] = acc * 0.25f;  // mean over 2x2 subsamples (invalid contribute 0)
}

extern "C" void kernel_launch(void* const* d_in, const int* in_sizes, int n_in,
                              void* d_out, int out_size, void* d_ws, size_t ws_size,
                              hipStream_t stream) {
    const float* f0    = (const float*)d_in[0];
    const float* f1    = (const float*)d_in[1];
    const float* f2    = (const float*)d_in[2];
    const float* f3    = (const float*)d_in[3];
    const float* boxes = (const float*)d_in[4];
    float* out = (float*)d_out;

    const int total = KTOT * CCH * PIX;   // 12,845,056
    const int block = 256;
    const int grid  = (total + block - 1) / block;

    msroi_kernel<<<grid, block, 0, stream>>>(f0, f1, f2, f3, boxes, out);
}